// Round 15
// baseline (1065.523 us; speedup 1.0000x reference)
//
#include <hip/hip_runtime.h>
#include <hip/hip_bf16.h>

#define NPAIR 4096
#define DIM   768            // fp8: 768 bytes per row
#define N2    8192
#define BM    256            // block rows (8 waves as 4x2, each 64x128)
#define BNB   256            // block cols per col-block
#define KBLK  64             // K tile bytes -> A,B tiles 16KB each; dbuf = 64KB
#define KITER (DIM / KBLK)   // 12
#define NSTRIP 16            // grid.y
#define CPB   ((N2 / BNB) / NSTRIP)    // 2 col-blocks per strip
#define NBI   (N2 / BM)      // 32
#define TOT   (CPB * KITER)  // 24 K-tile iterations per block

constexpr float INV_T = 1.0f / 0.07f;  // also the fixed softmax max M

typedef float f32x16 __attribute__((ext_vector_type(16)));
#define AS1 __attribute__((address_space(1)))
#define AS3 __attribute__((address_space(3)))

// ---------------- normalize: one wave per row, fp32 in -> fp8 e4m3 out ------
__global__ void knorm(const float* __restrict__ z1, const float* __restrict__ z2,
                      unsigned char* __restrict__ zq) {
    const int row  = blockIdx.x * 4 + (threadIdx.x >> 6);
    const int lane = threadIdx.x & 63;
    const float* src = (row < NPAIR) ? (z1 + (size_t)row * DIM)
                                     : (z2 + (size_t)(row - NPAIR) * DIM);
    float4 v[3];
    float ss = 0.f;
#pragma unroll
    for (int i = 0; i < 3; ++i) {
        v[i] = reinterpret_cast<const float4*>(src)[lane + 64 * i];
        ss += v[i].x * v[i].x + v[i].y * v[i].y + v[i].z * v[i].z + v[i].w * v[i].w;
    }
#pragma unroll
    for (int off = 32; off; off >>= 1) ss += __shfl_xor(ss, off);
    const float scale = 1.0f / fmaxf(sqrtf(ss), 1e-12f);
    unsigned int* dst = reinterpret_cast<unsigned int*>(zq + (size_t)row * DIM);
#pragma unroll
    for (int i = 0; i < 3; ++i) {
        unsigned int u = 0;
        u = __builtin_amdgcn_cvt_pk_fp8_f32(v[i].x * scale, v[i].y * scale, u, false);
        u = __builtin_amdgcn_cvt_pk_fp8_f32(v[i].z * scale, v[i].w * scale, u, true);
        dst[lane + 64 * i] = u;
    }
}

// ---------------- positive-pair dots from fp8 (consistent with klse) --------
__global__ void kpos(const unsigned char* __restrict__ zq, float* __restrict__ pos) {
    const int pair = blockIdx.x * 4 + (threadIdx.x >> 6);
    const int lane = threadIdx.x & 63;
    const unsigned int* a = reinterpret_cast<const unsigned int*>(zq + (size_t)pair * DIM);
    const unsigned int* b = reinterpret_cast<const unsigned int*>(zq + (size_t)(pair + NPAIR) * DIM);
    float s = 0.f;
#pragma unroll
    for (int i = 0; i < 3; ++i) {
        const unsigned int ua = a[lane + 64 * i];
        const unsigned int ub = b[lane + 64 * i];
        s += __builtin_amdgcn_cvt_f32_fp8(ua, 0) * __builtin_amdgcn_cvt_f32_fp8(ub, 0);
        s += __builtin_amdgcn_cvt_f32_fp8(ua, 1) * __builtin_amdgcn_cvt_f32_fp8(ub, 1);
        s += __builtin_amdgcn_cvt_f32_fp8(ua, 2) * __builtin_amdgcn_cvt_f32_fp8(ub, 2);
        s += __builtin_amdgcn_cvt_f32_fp8(ua, 3) * __builtin_amdgcn_cvt_f32_fp8(ub, 3);
    }
#pragma unroll
    for (int off = 32; off; off >>= 1) s += __shfl_xor(s, off);
    if (lane == 0) pos[pair] = s * INV_T;
}

// ---------------- main: 256^2 block, 8 waves, LDS-traffic-halved ------------
// Same proven 2-phase dbuf pipeline and swizzle as R11/R13; block scaled to
// 256x256 (8 waves, each 64 rows x 128 cols via acc[2][4] of 32x32x16 fp8).
// Per output element: staged writes 0.5x, fragment reads 0.75x vs 128^2 --
// attacks the measured CU-level LDS saturation. 64KB dbuf -> 2 blocks/CU,
// 16 waves/CU. Grid 32x16 = 512 = exactly 2/CU.
__global__ __launch_bounds__(512, 4) void klse(const unsigned char* __restrict__ zq,
                                               float* __restrict__ rowsum) {
    __shared__ __align__(16) unsigned char As[2][BM * KBLK];   // 2 x 16 KB
    __shared__ __align__(16) unsigned char Bs[2][BM * KBLK];   // 2 x 16 KB
    const int tid  = threadIdx.x;
    const int wave = tid >> 6;
    const int lane = tid & 63;
    const int wr = wave >> 1, wc = wave & 1;     // 4 row-groups x 2 col-groups
    const int hi = lane >> 5, rlo = lane & 31;
    const int bi = blockIdx.x;
    const int rb = bi * BM;

    const int sw = (rlo >> 1) & 3;               // row-pair swizzle class
    int raOff[2], cbOff[4];
#pragma unroll
    for (int m = 0; m < 2; ++m) raOff[m] = (wr * 64 + m * 32 + rlo) * KBLK;
#pragma unroll
    for (int n = 0; n < 4; ++n) cbOff[n] = (wc * 128 + n * 32 + rlo) * KBLK;

    // stage K-tile (ct,kt) into buffer buf: 1024 granules of 16B per matrix
    auto stage = [&](int ct, int kt, int buf) {
        const int c0 = (blockIdx.y * CPB + ct) * BNB;
        const int koff = kt * KBLK;
#pragma unroll
        for (int i = 0; i < 2; ++i) {
            const int g = i * 512 + tid;         // granule in [0,1024)
            const int r = g >> 2, s = g & 3;
            const int ks = koff + ((s ^ ((r >> 1) & 3)) << 4);
            __builtin_amdgcn_global_load_lds(
                (const AS1 unsigned int*)(zq + (size_t)(rb + r) * DIM + ks),
                (AS3 unsigned int*)(&As[buf][g * 16]), 16, 0, 0);
            __builtin_amdgcn_global_load_lds(
                (const AS1 unsigned int*)(zq + (size_t)(c0 + r) * DIM + ks),
                (AS3 unsigned int*)(&Bs[buf][g * 16]), 16, 0, 0);
        }
    };

    f32x16 acc[2][4];
#pragma unroll
    for (int m = 0; m < 2; ++m)
#pragma unroll
        for (int n = 0; n < 4; ++n) acc[m][n] = f32x16{};

    stage(0, 0, 0);
    asm volatile("s_waitcnt vmcnt(0)" ::: "memory");
    __builtin_amdgcn_s_barrier();

    int ct = 0, kt = 0;
    for (int it = 0; it < TOT; ++it) {
        const int cur = it & 1;
        int nct = ct, nkt = kt + 1;
        if (nkt == KITER) { nkt = 0; ++nct; }
        if (it + 1 < TOT) stage(nct, nkt, cur ^ 1);   // issue next-tile loads FIRST

        // compute on buf[cur]: 4 K-steps x 2x4 subtiles
#pragma unroll
        for (int ts = 0; ts < 4; ++ts) {
            const int so = ((ts ^ sw) << 4) + (hi << 3);  // swizzled octet offset
            long a[2], b[4];
#pragma unroll
            for (int m = 0; m < 2; ++m)
                a[m] = *reinterpret_cast<const long*>(&As[cur][raOff[m] + so]);
#pragma unroll
            for (int n = 0; n < 4; ++n)
                b[n] = *reinterpret_cast<const long*>(&Bs[cur][cbOff[n] + so]);
#pragma unroll
            for (int m = 0; m < 2; ++m)
#pragma unroll
                for (int n = 0; n < 4; ++n)
                    acc[m][n] = __builtin_amdgcn_mfma_f32_32x32x16_fp8_fp8(
                        a[m], b[n], acc[m][n], 0, 0, 0);
        }

        asm volatile("s_waitcnt vmcnt(0)" ::: "memory");  // next buffer landed
        __builtin_amdgcn_s_barrier();                     // all reads of buf done too

        if (kt == KITER - 1) {
            // ---------- epilogue for col-block ct: exp, mask, reduce --------
            const int cblk = blockIdx.y * CPB + ct;
            const bool on_diag = (cblk == bi);
#pragma unroll
            for (int m = 0; m < 2; ++m) {
                const int row0b = rb + wr * 64 + m * 32 + 4 * hi;
                float ps[16];
#pragma unroll
                for (int r = 0; r < 16; ++r) {
                    const int rg = row0b + (r & 3) + 8 * (r >> 2);
                    float e = 0.f;
#pragma unroll
                    for (int n = 0; n < 4; ++n) {
                        const int colg = cblk * BNB + wc * 128 + n * 32 + rlo;
                        float en = __expf((acc[m][n][r] - 1.0f) * INV_T);
                        if (on_diag && rg == colg) en = 0.f;
                        e += en;
                    }
                    ps[r] = e;
                }
#pragma unroll
                for (int r = 0; r < 16; ++r) {
#pragma unroll
                    for (int msk = 1; msk < 32; msk <<= 1)
                        ps[r] += __shfl_xor(ps[r], msk);
                }
                if (rlo == 0) {
#pragma unroll
                    for (int r = 0; r < 16; ++r)
                        atomicAdd(&rowsum[row0b + (r & 3) + 8 * (r >> 2)], ps[r]);
                }
#pragma unroll
                for (int n = 0; n < 4; ++n) acc[m][n] = f32x16{};
            }
        }
        ct = nct; kt = nkt;
    }
}

// ---------------- final: loss = mean(M + log S_i - pos) ---------------------
__global__ void kfinal(const float* __restrict__ rowsum, const float* __restrict__ pos,
                       float* __restrict__ out) {
    __shared__ float red[8];
    const int tid = threadIdx.x;
    float s = 0.f;
    for (int i = tid; i < N2; i += 512) {
        const int p = (i < NPAIR) ? i : i - NPAIR;
        s += INV_T + __logf(rowsum[i]) - pos[p];
    }
#pragma unroll
    for (int off = 32; off; off >>= 1) s += __shfl_xor(s, off);
    if ((tid & 63) == 0) red[tid >> 6] = s;
    __syncthreads();
    if (tid == 0) {
        float t = 0.f;
#pragma unroll
        for (int w = 0; w < 8; ++w) t += red[w];
        out[0] = t / (float)N2;
    }
}

extern "C" void kernel_launch(void* const* d_in, const int* in_sizes, int n_in,
                              void* d_out, int out_size, void* d_ws, size_t ws_size,
                              hipStream_t stream) {
    const float* z1 = (const float*)d_in[0];
    const float* z2 = (const float*)d_in[1];
    unsigned char* zq = (unsigned char*)d_ws;                         // 8192*768 fp8
    float* rowsum = (float*)((char*)d_ws + (size_t)N2 * DIM);         // 8192 f32
    float* pos = rowsum + N2;                                         // 4096 f32
    float* out = (float*)d_out;

    hipLaunchKernelGGL(knorm, dim3(N2 / 4), dim3(256), 0, stream, z1, z2, zq);
    hipLaunchKernelGGL(kpos, dim3(NPAIR / 4), dim3(256), 0, stream, zq, pos);
    hipMemsetAsync(rowsum, 0, N2 * sizeof(float), stream);
    hipLaunchKernelGGL(klse, dim3(NBI, NSTRIP), dim3(512), 0, stream, zq, rowsum);
    hipLaunchKernelGGL(kfinal, dim3(1), dim3(512), 0, stream, rowsum, pos, out);
}

// Round 16
// 133.565 us; speedup vs baseline: 7.9776x; 7.9776x over previous
//
#include <hip/hip_runtime.h>
#include <hip/hip_bf16.h>

#define NPAIR 4096
#define DIM   768            // fp8: 768 bytes per row
#define N2    8192
#define BM    256            // block rows (8 waves as 4x2, each 64x64)
#define BNB   128            // block cols per col-block
#define KBLK  64             // K tile bytes: A=16KB, B=8KB; dbuf = 48KB
#define KITER (DIM / KBLK)   // 12
#define NSTRIP 16            // grid.y
#define CPB   ((N2 / BNB) / NSTRIP)    // 4 col-blocks per strip
#define NBI   (N2 / BM)      // 32
#define TOT   (CPB * KITER)  // 48 K-tile iterations per block

constexpr float INV_T = 1.0f / 0.07f;  // also the fixed softmax max M

typedef float f32x16 __attribute__((ext_vector_type(16)));
#define AS1 __attribute__((address_space(1)))
#define AS3 __attribute__((address_space(3)))

// ---------------- normalize: one wave per row, fp32 in -> fp8 e4m3 out ------
__global__ void knorm(const float* __restrict__ z1, const float* __restrict__ z2,
                      unsigned char* __restrict__ zq) {
    const int row  = blockIdx.x * 4 + (threadIdx.x >> 6);
    const int lane = threadIdx.x & 63;
    const float* src = (row < NPAIR) ? (z1 + (size_t)row * DIM)
                                     : (z2 + (size_t)(row - NPAIR) * DIM);
    float4 v[3];
    float ss = 0.f;
#pragma unroll
    for (int i = 0; i < 3; ++i) {
        v[i] = reinterpret_cast<const float4*>(src)[lane + 64 * i];
        ss += v[i].x * v[i].x + v[i].y * v[i].y + v[i].z * v[i].z + v[i].w * v[i].w;
    }
#pragma unroll
    for (int off = 32; off; off >>= 1) ss += __shfl_xor(ss, off);
    const float scale = 1.0f / fmaxf(sqrtf(ss), 1e-12f);
    unsigned int* dst = reinterpret_cast<unsigned int*>(zq + (size_t)row * DIM);
#pragma unroll
    for (int i = 0; i < 3; ++i) {
        unsigned int u = 0;
        u = __builtin_amdgcn_cvt_pk_fp8_f32(v[i].x * scale, v[i].y * scale, u, false);
        u = __builtin_amdgcn_cvt_pk_fp8_f32(v[i].z * scale, v[i].w * scale, u, true);
        dst[lane + 64 * i] = u;
    }
}

// ---------------- positive-pair dots from fp8 (consistent with klse) --------
__global__ void kpos(const unsigned char* __restrict__ zq, float* __restrict__ pos) {
    const int pair = blockIdx.x * 4 + (threadIdx.x >> 6);
    const int lane = threadIdx.x & 63;
    const unsigned int* a = reinterpret_cast<const unsigned int*>(zq + (size_t)pair * DIM);
    const unsigned int* b = reinterpret_cast<const unsigned int*>(zq + (size_t)(pair + NPAIR) * DIM);
    float s = 0.f;
#pragma unroll
    for (int i = 0; i < 3; ++i) {
        const unsigned int ua = a[lane + 64 * i];
        const unsigned int ub = b[lane + 64 * i];
        s += __builtin_amdgcn_cvt_f32_fp8(ua, 0) * __builtin_amdgcn_cvt_f32_fp8(ub, 0);
        s += __builtin_amdgcn_cvt_f32_fp8(ua, 1) * __builtin_amdgcn_cvt_f32_fp8(ub, 1);
        s += __builtin_amdgcn_cvt_f32_fp8(ua, 2) * __builtin_amdgcn_cvt_f32_fp8(ub, 2);
        s += __builtin_amdgcn_cvt_f32_fp8(ua, 3) * __builtin_amdgcn_cvt_f32_fp8(ub, 3);
    }
#pragma unroll
    for (int off = 32; off; off >>= 1) s += __shfl_xor(s, off);
    if (lane == 0) pos[pair] = s * INV_T;
}

// ---------------- main: 256x128 block, 8 waves of 64x64 ---------------------
// Same 2-phase dbuf pipeline + 4-way swizzle as R11/R13. Block = 256 rows x
// 128 cols, 8 waves (4x2), each 64x64 via acc 2x2 of 32x32x16 fp8 MFMA.
// Per output: staged writes 0.75x, barriers 0.5x vs 128^2; reads at HW floor.
// acc[2][2]=64 AGPR + ~50 VGPR = ~114 <= 128-cap of __launch_bounds__(512,4)
// (R14 died at 184 > 128 -> scratch). LDS 48KB dbuf -> 2 blocks/CU, 16 w/CU.
__global__ __launch_bounds__(512, 4) void klse(const unsigned char* __restrict__ zq,
                                               float* __restrict__ rowsum) {
    __shared__ __align__(16) unsigned char As[2][BM * KBLK];    // 2 x 16 KB
    __shared__ __align__(16) unsigned char Bs[2][BNB * KBLK];   // 2 x 8 KB
    const int tid  = threadIdx.x;
    const int wave = tid >> 6;
    const int lane = tid & 63;
    const int wr = wave >> 1, wc = wave & 1;     // 4 row-groups x 2 col-groups
    const int hi = lane >> 5, rlo = lane & 31;
    const int bi = blockIdx.x;
    const int rb = bi * BM;

    const int sw  = (rlo >> 1) & 3;              // row-pair swizzle class
    const int raA = (wr * 64 + rlo) * KBLK;      // A sub 0 row base (bytes)
    const int raB = raA + 32 * KBLK;             // A sub 1
    const int caA = (wc * 64 + rlo) * KBLK;      // B sub 0 col base
    const int caB = caA + 32 * KBLK;             // B sub 1

    // stage K-tile (ct,kt): A = 1024 granules (2/thread), B = 512 (1/thread)
    auto stage = [&](int ct, int kt, int buf) {
        const int c0 = (blockIdx.y * CPB + ct) * BNB;
        const int koff = kt * KBLK;
#pragma unroll
        for (int i = 0; i < 2; ++i) {
            const int g = i * 512 + tid;         // A granule in [0,1024)
            const int r = g >> 2, s = g & 3;
            const int ks = koff + ((s ^ ((r >> 1) & 3)) << 4);
            __builtin_amdgcn_global_load_lds(
                (const AS1 unsigned int*)(zq + (size_t)(rb + r) * DIM + ks),
                (AS3 unsigned int*)(&As[buf][g * 16]), 16, 0, 0);
        }
        {
            const int g = tid;                   // B granule in [0,512)
            const int r = g >> 2, s = g & 3;
            const int ks = koff + ((s ^ ((r >> 1) & 3)) << 4);
            __builtin_amdgcn_global_load_lds(
                (const AS1 unsigned int*)(zq + (size_t)(c0 + r) * DIM + ks),
                (AS3 unsigned int*)(&Bs[buf][g * 16]), 16, 0, 0);
        }
    };

    f32x16 acc00 = {}, acc01 = {}, acc10 = {}, acc11 = {};

    stage(0, 0, 0);
    asm volatile("s_waitcnt vmcnt(0)" ::: "memory");
    __builtin_amdgcn_s_barrier();

    int ct = 0, kt = 0;
    for (int it = 0; it < TOT; ++it) {
        const int cur = it & 1;
        int nct = ct, nkt = kt + 1;
        if (nkt == KITER) { nkt = 0; ++nct; }
        if (it + 1 < TOT) stage(nct, nkt, cur ^ 1);   // issue next-tile loads FIRST

        // compute on buf[cur]: 4 K-steps x 2x2 subtiles
#pragma unroll
        for (int ts = 0; ts < 4; ++ts) {
            const int so = ((ts ^ sw) << 4) + (hi << 3);  // swizzled octet offset
            long a0 = *reinterpret_cast<const long*>(&As[cur][raA + so]);
            long a1 = *reinterpret_cast<const long*>(&As[cur][raB + so]);
            long b0 = *reinterpret_cast<const long*>(&Bs[cur][caA + so]);
            long b1 = *reinterpret_cast<const long*>(&Bs[cur][caB + so]);
            acc00 = __builtin_amdgcn_mfma_f32_32x32x16_fp8_fp8(a0, b0, acc00, 0, 0, 0);
            acc01 = __builtin_amdgcn_mfma_f32_32x32x16_fp8_fp8(a0, b1, acc01, 0, 0, 0);
            acc10 = __builtin_amdgcn_mfma_f32_32x32x16_fp8_fp8(a1, b0, acc10, 0, 0, 0);
            acc11 = __builtin_amdgcn_mfma_f32_32x32x16_fp8_fp8(a1, b1, acc11, 0, 0, 0);
        }

        asm volatile("s_waitcnt vmcnt(0)" ::: "memory");  // next buffer landed
        __builtin_amdgcn_s_barrier();                     // all reads of buf done too

        if (kt == KITER - 1) {
            // ---------- epilogue for col-block ct: exp, mask, reduce --------
            const int cblk = blockIdx.y * CPB + ct;
            const int cb0 = cblk * BNB;
            const bool on_diag = (cb0 + BNB > rb) && (cb0 < rb + BM);
            const int row0b = rb + wr * 64 + 4 * hi;
            const int colg  = cb0 + wc * 64 + rlo;
            float ps0[16], ps1[16];
#pragma unroll
            for (int r = 0; r < 16; ++r) {
                const int rg0 = row0b + (r & 3) + 8 * (r >> 2);
                float e00 = __expf((acc00[r] - 1.0f) * INV_T);
                float e01 = __expf((acc01[r] - 1.0f) * INV_T);
                float e10 = __expf((acc10[r] - 1.0f) * INV_T);
                float e11 = __expf((acc11[r] - 1.0f) * INV_T);
                if (on_diag) {
                    if (rg0 == colg)           e00 = 0.f;
                    if (rg0 == colg + 32)      e01 = 0.f;
                    if (rg0 + 32 == colg)      e10 = 0.f;
                    if (rg0 + 32 == colg + 32) e11 = 0.f;
                }
                ps0[r] = e00 + e01;
                ps1[r] = e10 + e11;
            }
#pragma unroll
            for (int r = 0; r < 16; ++r) {
#pragma unroll
                for (int m = 1; m < 32; m <<= 1) {
                    ps0[r] += __shfl_xor(ps0[r], m);
                    ps1[r] += __shfl_xor(ps1[r], m);
                }
            }
            if (rlo == 0) {
#pragma unroll
                for (int r = 0; r < 16; ++r) {
                    const int rg0 = row0b + (r & 3) + 8 * (r >> 2);
                    atomicAdd(&rowsum[rg0], ps0[r]);
                    atomicAdd(&rowsum[rg0 + 32], ps1[r]);
                }
            }
            acc00 = f32x16{}; acc01 = f32x16{};
            acc10 = f32x16{}; acc11 = f32x16{};
        }
        ct = nct; kt = nkt;
    }
}

// ---------------- final: loss = mean(M + log S_i - pos) ---------------------
__global__ void kfinal(const float* __restrict__ rowsum, const float* __restrict__ pos,
                       float* __restrict__ out) {
    __shared__ float red[8];
    const int tid = threadIdx.x;
    float s = 0.f;
    for (int i = tid; i < N2; i += 512) {
        const int p = (i < NPAIR) ? i : i - NPAIR;
        s += INV_T + __logf(rowsum[i]) - pos[p];
    }
#pragma unroll
    for (int off = 32; off; off >>= 1) s += __shfl_xor(s, off);
    if ((tid & 63) == 0) red[tid >> 6] = s;
    __syncthreads();
    if (tid == 0) {
        float t = 0.f;
#pragma unroll
        for (int w = 0; w < 8; ++w) t += red[w];
        out[0] = t / (float)N2;
    }
}

extern "C" void kernel_launch(void* const* d_in, const int* in_sizes, int n_in,
                              void* d_out, int out_size, void* d_ws, size_t ws_size,
                              hipStream_t stream) {
    const float* z1 = (const float*)d_in[0];
    const float* z2 = (const float*)d_in[1];
    unsigned char* zq = (unsigned char*)d_ws;                         // 8192*768 fp8
    float* rowsum = (float*)((char*)d_ws + (size_t)N2 * DIM);         // 8192 f32
    float* pos = rowsum + N2;                                         // 4096 f32
    float* out = (float*)d_out;

    hipLaunchKernelGGL(knorm, dim3(N2 / 4), dim3(256), 0, stream, z1, z2, zq);
    hipLaunchKernelGGL(kpos, dim3(NPAIR / 4), dim3(256), 0, stream, zq, pos);
    hipMemsetAsync(rowsum, 0, N2 * sizeof(float), stream);
    hipLaunchKernelGGL(klse, dim3(NBI, NSTRIP), dim3(512), 0, stream, zq, rowsum);
    hipLaunchKernelGGL(kfinal, dim3(1), dim3(512), 0, stream, rowsum, pos, out);
}

// Round 17
// 104.293 us; speedup vs baseline: 10.2166x; 1.2807x over previous
//
#include <hip/hip_runtime.h>
#include <hip/hip_bf16.h>

#define NPAIR 4096
#define DIM   768            // fp8: 768 bytes per row
#define N2    8192
#define BM    128            // block rows (4 waves as 2x2, each 64x64)
#define BNB   128            // block cols per col-block
#define KBLK  64             // K tile bytes; dbuf = 32KB total
#define KITER (DIM / KBLK)   // 12
#define NSTRIP 16            // grid.y
#define CPB   ((N2 / BNB) / NSTRIP)    // 4 col-blocks per strip
#define NBI   (N2 / BM)      // 64
#define TOT   (CPB * KITER)  // 48 K-tile iterations per block
#define SC1   0x7F7F7F7F     // packed E8M0 scales: all 1.0

constexpr float INV_T = 1.0f / 0.07f;  // also the fixed softmax max M

typedef float f32x16 __attribute__((ext_vector_type(16)));
typedef int   i32x8  __attribute__((ext_vector_type(8)));
#define AS1 __attribute__((address_space(1)))
#define AS3 __attribute__((address_space(3)))

// ---------------- normalize: one wave per row, fp32 in -> fp8 e4m3 out ------
__global__ void knorm(const float* __restrict__ z1, const float* __restrict__ z2,
                      unsigned char* __restrict__ zq) {
    const int row  = blockIdx.x * 4 + (threadIdx.x >> 6);
    const int lane = threadIdx.x & 63;
    const float* src = (row < NPAIR) ? (z1 + (size_t)row * DIM)
                                     : (z2 + (size_t)(row - NPAIR) * DIM);
    float4 v[3];
    float ss = 0.f;
#pragma unroll
    for (int i = 0; i < 3; ++i) {
        v[i] = reinterpret_cast<const float4*>(src)[lane + 64 * i];
        ss += v[i].x * v[i].x + v[i].y * v[i].y + v[i].z * v[i].z + v[i].w * v[i].w;
    }
#pragma unroll
    for (int off = 32; off; off >>= 1) ss += __shfl_xor(ss, off);
    const float scale = 1.0f / fmaxf(sqrtf(ss), 1e-12f);
    unsigned int* dst = reinterpret_cast<unsigned int*>(zq + (size_t)row * DIM);
#pragma unroll
    for (int i = 0; i < 3; ++i) {
        unsigned int u = 0;
        u = __builtin_amdgcn_cvt_pk_fp8_f32(v[i].x * scale, v[i].y * scale, u, false);
        u = __builtin_amdgcn_cvt_pk_fp8_f32(v[i].z * scale, v[i].w * scale, u, true);
        dst[lane + 64 * i] = u;
    }
}

// ---------------- positive-pair dots from fp8 (consistent with klse) --------
__global__ void kpos(const unsigned char* __restrict__ zq, float* __restrict__ pos) {
    const int pair = blockIdx.x * 4 + (threadIdx.x >> 6);
    const int lane = threadIdx.x & 63;
    const unsigned int* a = reinterpret_cast<const unsigned int*>(zq + (size_t)pair * DIM);
    const unsigned int* b = reinterpret_cast<const unsigned int*>(zq + (size_t)(pair + NPAIR) * DIM);
    float s = 0.f;
#pragma unroll
    for (int i = 0; i < 3; ++i) {
        const unsigned int ua = a[lane + 64 * i];
        const unsigned int ub = b[lane + 64 * i];
        s += __builtin_amdgcn_cvt_f32_fp8(ua, 0) * __builtin_amdgcn_cvt_f32_fp8(ub, 0);
        s += __builtin_amdgcn_cvt_f32_fp8(ua, 1) * __builtin_amdgcn_cvt_f32_fp8(ub, 1);
        s += __builtin_amdgcn_cvt_f32_fp8(ua, 2) * __builtin_amdgcn_cvt_f32_fp8(ub, 2);
        s += __builtin_amdgcn_cvt_f32_fp8(ua, 3) * __builtin_amdgcn_cvt_f32_fp8(ub, 3);
    }
#pragma unroll
    for (int off = 32; off; off >>= 1) s += __shfl_xor(s, off);
    if (lane == 0) pos[pair] = s * INV_T;
}

// ---------------- main: R11 pipeline + MX-scaled MFMA (K=64) ----------------
// Per iter: 8 ds_read_b128 + 4 mfma_scale_f32_32x32x64_f8f6f4 (scales=1.0).
// Same 2-phase dbuf (stage-first, one vmcnt(0)+barrier), 32KB LDS, 4-way
// uniform swizzle. Epilogue deferred: per-lane rowacc across col-tiles, ONE
// butterfly+atomics per block (DS epilogue cost /4). Addressing hoisted.
__global__ __launch_bounds__(256, 3) void klse(const unsigned char* __restrict__ zq,
                                               float* __restrict__ rowsum) {
    __shared__ __align__(16) unsigned char As[2][BM * KBLK];   // 2 x 8 KB
    __shared__ __align__(16) unsigned char Bs[2][BM * KBLK];   // 2 x 8 KB
    const int tid  = threadIdx.x;
    const int wave = tid >> 6;
    const int lane = tid & 63;
    const int wr = wave >> 1, wc = wave & 1;
    const int hi = lane >> 5, rlo = lane & 31;
    const int bi = blockIdx.x;
    const int rb = bi * BM;

    // ---- staging geometry (per-thread, loop-invariant) ----
    const int sr   = tid >> 2;                 // row within 64-row group
    const int soff = (((tid & 3) ^ ((sr >> 1) & 3)) << 4);  // swizzled src offset
    const size_t offA0 = (size_t)(rb + sr) * DIM + soff;
    const size_t offA1 = (size_t)(rb + 64 + sr) * DIM + soff;
    const size_t offB0 = (size_t)sr * DIM + soff;            // + c0*DIM at use
    const size_t offB1 = (size_t)(64 + sr) * DIM + soff;

    auto stage = [&](int c0, int koff, int buf) {
        __builtin_amdgcn_global_load_lds(
            (const AS1 unsigned int*)(zq + offA0 + koff),
            (AS3 unsigned int*)(&As[buf][tid * 16]), 16, 0, 0);
        __builtin_amdgcn_global_load_lds(
            (const AS1 unsigned int*)(zq + offA1 + koff),
            (AS3 unsigned int*)(&As[buf][4096 + tid * 16]), 16, 0, 0);
        __builtin_amdgcn_global_load_lds(
            (const AS1 unsigned int*)(zq + (size_t)c0 * DIM + offB0 + koff),
            (AS3 unsigned int*)(&Bs[buf][tid * 16]), 16, 0, 0);
        __builtin_amdgcn_global_load_lds(
            (const AS1 unsigned int*)(zq + (size_t)c0 * DIM + offB1 + koff),
            (AS3 unsigned int*)(&Bs[buf][4096 + tid * 16]), 16, 0, 0);
    };

    // ---- fragment-read geometry (constant per iter) ----
    const int sw  = (rlo >> 1) & 3;
    const int pg0 = ((2 * hi) ^ sw) << 4;      // first b128 (16B granule)
    const int pg1 = ((2 * hi + 1) ^ sw) << 4;  // second b128
    const int raA = (wr * 64 + rlo) * KBLK;
    const int raB = raA + 32 * KBLK;
    const int caA = (wc * 64 + rlo) * KBLK;
    const int caB = caA + 32 * KBLK;

    auto ldf = [&](const unsigned char* p) -> i32x8 {
        int4 u = *reinterpret_cast<const int4*>(p + pg0);
        int4 v = *reinterpret_cast<const int4*>(p + pg1);
        return i32x8{u.x, u.y, u.z, u.w, v.x, v.y, v.z, v.w};
    };

    f32x16 acc00 = {}, acc01 = {}, acc10 = {}, acc11 = {};
    float rowacc0[16], rowacc1[16];
#pragma unroll
    for (int r = 0; r < 16; ++r) { rowacc0[r] = 0.f; rowacc1[r] = 0.f; }
    const int row0b = rb + wr * 64 + 4 * hi;

    stage(blockIdx.y * CPB * BNB, 0, 0);
    asm volatile("s_waitcnt vmcnt(0)" ::: "memory");
    __builtin_amdgcn_s_barrier();

    int ct = 0, kt = 0;
    for (int it = 0; it < TOT; ++it) {
        const int cur = it & 1;
        int nct = ct, nkt = kt + 1;
        if (nkt == KITER) { nkt = 0; ++nct; }
        if (it + 1 < TOT)
            stage((blockIdx.y * CPB + nct) * BNB, nkt * KBLK, cur ^ 1);

        i32x8 a0 = ldf(&As[cur][raA]);
        i32x8 a1 = ldf(&As[cur][raB]);
        i32x8 b0 = ldf(&Bs[cur][caA]);
        i32x8 b1 = ldf(&Bs[cur][caB]);
        acc00 = __builtin_amdgcn_mfma_scale_f32_32x32x64_f8f6f4(a0, b0, acc00, 0, 0, 0, SC1, 0, SC1);
        acc01 = __builtin_amdgcn_mfma_scale_f32_32x32x64_f8f6f4(a0, b1, acc01, 0, 0, 0, SC1, 0, SC1);
        acc10 = __builtin_amdgcn_mfma_scale_f32_32x32x64_f8f6f4(a1, b0, acc10, 0, 0, 0, SC1, 0, SC1);
        acc11 = __builtin_amdgcn_mfma_scale_f32_32x32x64_f8f6f4(a1, b1, acc11, 0, 0, 0, SC1, 0, SC1);

        asm volatile("s_waitcnt vmcnt(0)" ::: "memory");  // next buffer landed
        __builtin_amdgcn_s_barrier();                     // all reads of buf done

        if (kt == KITER - 1) {
            // exp + mask + per-lane accumulate (no shuffles here)
            const int cblk = blockIdx.y * CPB + ct;
            const bool on_diag = (cblk == bi);
            const int colg = cblk * BNB + wc * 64 + rlo;
#pragma unroll
            for (int r = 0; r < 16; ++r) {
                const int rg0 = row0b + (r & 3) + 8 * (r >> 2);
                float e00 = __expf((acc00[r] - 1.0f) * INV_T);
                float e01 = __expf((acc01[r] - 1.0f) * INV_T);
                float e10 = __expf((acc10[r] - 1.0f) * INV_T);
                float e11 = __expf((acc11[r] - 1.0f) * INV_T);
                if (on_diag) {
                    if (rg0 == colg)           e00 = 0.f;
                    if (rg0 == colg + 32)      e01 = 0.f;
                    if (rg0 + 32 == colg)      e10 = 0.f;
                    if (rg0 + 32 == colg + 32) e11 = 0.f;
                }
                rowacc0[r] += e00 + e01;
                rowacc1[r] += e10 + e11;
            }
            acc00 = f32x16{}; acc01 = f32x16{};
            acc10 = f32x16{}; acc11 = f32x16{};
        }
        ct = nct; kt = nkt;
    }

    // block end: ONE butterfly over 32 col-lanes + atomics
#pragma unroll
    for (int r = 0; r < 16; ++r) {
#pragma unroll
        for (int m = 1; m < 32; m <<= 1) {
            rowacc0[r] += __shfl_xor(rowacc0[r], m);
            rowacc1[r] += __shfl_xor(rowacc1[r], m);
        }
    }
    if (rlo == 0) {
#pragma unroll
        for (int r = 0; r < 16; ++r) {
            const int rg0 = row0b + (r & 3) + 8 * (r >> 2);
            atomicAdd(&rowsum[rg0], rowacc0[r]);
            atomicAdd(&rowsum[rg0 + 32], rowacc1[r]);
        }
    }
}

// ---------------- final: loss = mean(M + log S_i - pos) ---------------------
__global__ void kfinal(const float* __restrict__ rowsum, const float* __restrict__ pos,
                       float* __restrict__ out) {
    __shared__ float red[8];
    const int tid = threadIdx.x;
    float s = 0.f;
    for (int i = tid; i < N2; i += 512) {
        const int p = (i < NPAIR) ? i : i - NPAIR;
        s += INV_T + __logf(rowsum[i]) - pos[p];
    }
#pragma unroll
    for (int off = 32; off; off >>= 1) s += __shfl_xor(s, off);
    if ((tid & 63) == 0) red[tid >> 6] = s;
    __syncthreads();
    if (tid == 0) {
        float t = 0.f;
#pragma unroll
        for (int w = 0; w < 8; ++w) t += red[w];
        out[0] = t / (float)N2;
    }
}

extern "C" void kernel_launch(void* const* d_in, const int* in_sizes, int n_in,
                              void* d_out, int out_size, void* d_ws, size_t ws_size,
                              hipStream_t stream) {
    const float* z1 = (const float*)d_in[0];
    const float* z2 = (const float*)d_in[1];
    unsigned char* zq = (unsigned char*)d_ws;                         // 8192*768 fp8
    float* rowsum = (float*)((char*)d_ws + (size_t)N2 * DIM);         // 8192 f32
    float* pos = rowsum + N2;                                         // 4096 f32
    float* out = (float*)d_out;

    hipLaunchKernelGGL(knorm, dim3(N2 / 4), dim3(256), 0, stream, z1, z2, zq);
    hipLaunchKernelGGL(kpos, dim3(NPAIR / 4), dim3(256), 0, stream, zq, pos);
    hipMemsetAsync(rowsum, 0, N2 * sizeof(float), stream);
    hipLaunchKernelGGL(klse, dim3(NBI, NSTRIP), dim3(256), 0, stream, zq, rowsum);
    hipLaunchKernelGGL(kfinal, dim3(1), dim3(512), 0, stream, rowsum, pos, out);
}